// Round 14
// baseline (32.350 us; speedup 1.0000x reference)
//
#include <hip/hip_runtime.h>
#include <math.h>
#include <string.h>

#define NJ 24
#define NV 6890
#define NB 128
#define VPB 1024     // verts per block
#define VPR 128      // verts per round
#define NR 8         // rounds per block
#define TLSTRIDE 20  // floats per tl row

// Ancestor chains (closest ancestor first), -1 padded. Max depth 8.
__constant__ int d_anc[NJ][8] = {
  {-1,-1,-1,-1,-1,-1,-1,-1},
  { 0,-1,-1,-1,-1,-1,-1,-1},
  { 0,-1,-1,-1,-1,-1,-1,-1},
  { 0,-1,-1,-1,-1,-1,-1,-1},
  { 1, 0,-1,-1,-1,-1,-1,-1},
  { 2, 0,-1,-1,-1,-1,-1,-1},
  { 3, 0,-1,-1,-1,-1,-1,-1},
  { 4, 1, 0,-1,-1,-1,-1,-1},
  { 5, 2, 0,-1,-1,-1,-1,-1},
  { 6, 3, 0,-1,-1,-1,-1,-1},
  { 7, 4, 1, 0,-1,-1,-1,-1},
  { 8, 5, 2, 0,-1,-1,-1,-1},
  { 9, 6, 3, 0,-1,-1,-1,-1},
  { 9, 6, 3, 0,-1,-1,-1,-1},
  { 9, 6, 3, 0,-1,-1,-1,-1},
  {12, 9, 6, 3, 0,-1,-1,-1},
  {13, 9, 6, 3, 0,-1,-1,-1},
  {14, 9, 6, 3, 0,-1,-1,-1},
  {16,13, 9, 6, 3, 0,-1,-1},
  {17,14, 9, 6, 3, 0,-1,-1},
  {18,16,13, 9, 6, 3, 0,-1},
  {19,17,14, 9, 6, 3, 0,-1},
  {20,18,16,13, 9, 6, 3, 0},
  {21,19,17,14, 9, 6, 3, 0}
};
__constant__ int d_par[NJ] = {-1,0,0,0,1,2,3,4,5,6,7,8,9,9,9,12,13,14,16,17,18,19,20,21};

typedef __attribute__((ext_vector_type(8))) short bf16x8;
typedef __attribute__((ext_vector_type(4))) float f32x4;
typedef __attribute__((address_space(3))) void lds_vt;
typedef const __attribute__((address_space(1))) void gm_vt;

__device__ __forceinline__ short f2bf(float f) {
    unsigned int u;
    memcpy(&u, &f, 4);
    u += 0x7fffu + ((u >> 16) & 1u);   // round-to-nearest-even
    return (short)(u >> 16);
}

// Stage one 128-vert round of W (12 KB = 768 float4) direct to LDS.
// Per thread: 3 global_load_lds_dwordx4. LDS dest = uniform base + lane*16
// (linear layout, matching HW semantics).
__device__ __forceinline__ void stage_round(const float* __restrict__ wsrc,
                                            float* ldsbuf, int tid) {
    #pragma unroll
    for (int i = 0; i < 3; i++) {
        const int idx = i * 256 + tid;   // float4 index within the 12 KB round
        __builtin_amdgcn_global_load_lds((gm_vt*)(wsrc + idx * 4),
                                         (lds_vt*)(ldsbuf + idx * 4),
                                         16, 0, 0);
    }
}

// FUSED kernel, direct-to-LDS W streaming (tests the per-CU miss-queue
// hypothesis): W is staged via global_load_lds into a 3-buffer LDS ring,
// distance-2 prefetch, ~12 KB/block in flight through each round's compute.
// MFMA skinning consumes A-fragments from LDS; B-fragment (Gc) in 4 VGPRs.
// Block covers 1024 verts in 8 rounds of 128; last block overlaps its
// predecessor (vstart = NV-1024) so every access is in-bounds, no guards.
__global__ __launch_bounds__(256, 3) void lbs_fused(const float* __restrict__ V,
                                                    const float* __restrict__ J,
                                                    const float* __restrict__ pose,
                                                    const float* __restrict__ W,
                                                    float* __restrict__ out) {
    const int b    = blockIdx.y;
    const int tid  = threadIdx.x;
    const int wave = tid >> 6;
    const int lane = tid & 63;
    const int n16  = lane & 15;   // A: vertex slot | B: out-elem n | C: col
    const int g    = lane >> 4;   // k-group (8 joints per group)
    const int vstart = (blockIdx.x < (NV / VPB)) ? blockIdx.x * VPB : (NV - VPB);

    __shared__ float A_lds[NJ][12];
    __shared__ float Gc_lds[NJ * 12];
    __shared__ float Wbuf[3][VPR * 24];          // 3 x 12 KB ring
    __shared__ float tl[4 * 32 * TLSTRIDE];      // 4 waves x 32 verts x 20

    const float* wbase = W + ((size_t)b * NV + vstart) * 24;

    // ---- Prologue: stage rounds 0,1 + V(0) prefetch (in flight under chain)
    stage_round(wbase + 0 * VPR * 24, Wbuf[0], tid);
    stage_round(wbase + 1 * VPR * 24, Wbuf[1], tid);

    float vnx = 0.f, vny = 0.f, vnz = 0.f;
    if (lane < 32) {
        const float* vp = V + ((size_t)b * NV + vstart + wave * 32 + lane) * 3;
        vnx = vp[0]; vny = vp[1]; vnz = vp[2];
    }

    // ---- Phase 0: chain ----
    if (tid < NJ) {
        const int i = tid;
        const float* p = pose + ((size_t)b * NJ + i) * 3;
        float rx = p[0], ry = p[1], rz = p[2];
        float ex = rx + 1e-8f, ey = ry + 1e-8f, ez = rz + 1e-8f;
        float theta = sqrtf(ex * ex + ey * ey + ez * ez);
        float inv = 1.0f / theta;
        float hx = rx * inv, hy = ry * inv, hz = rz * inv;
        float c = cosf(theta * (float)M_PI);
        float s = sinf(theta);
        float oc = 1.0f - c;
        const float* jp = J + ((size_t)b * NJ + i) * 3;
        int par = d_par[i];
        float tx, ty, tz;
        if (par < 0) {
            tx = jp[0]; ty = jp[1]; tz = jp[2];
        } else {
            const float* jq = J + ((size_t)b * NJ + par) * 3;
            tx = jp[0] - jq[0]; ty = jp[1] - jq[1]; tz = jp[2] - jq[2];
        }
        A_lds[i][0]  = c + oc * hx * hx;
        A_lds[i][1]  = oc * hx * hy - s * hz;
        A_lds[i][2]  = oc * hx * hz + s * hy;
        A_lds[i][3]  = tx;
        A_lds[i][4]  = oc * hy * hx + s * hz;
        A_lds[i][5]  = c + oc * hy * hy;
        A_lds[i][6]  = oc * hy * hz - s * hx;
        A_lds[i][7]  = ty;
        A_lds[i][8]  = oc * hz * hx - s * hy;
        A_lds[i][9]  = oc * hz * hy + s * hx;
        A_lds[i][10] = c + oc * hz * hz;
        A_lds[i][11] = tz;
    }
    __syncthreads();

    if (tid < NJ) {
        const int i = tid;
        float M[12];
        #pragma unroll
        for (int j = 0; j < 12; j++) M[j] = A_lds[i][j];

        for (int k = 0; k < 8; k++) {
            int p = d_anc[i][k];
            if (p < 0) break;
            float P[12];
            #pragma unroll
            for (int j = 0; j < 12; j++) P[j] = A_lds[p][j];
            float N[12];
            #pragma unroll
            for (int r = 0; r < 3; r++) {
                float p0 = P[r*4+0], p1 = P[r*4+1], p2 = P[r*4+2], p3 = P[r*4+3];
                N[r*4+0] = p0 * M[0] + p1 * M[4] + p2 * M[8];
                N[r*4+1] = p0 * M[1] + p1 * M[5] + p2 * M[9];
                N[r*4+2] = p0 * M[2] + p1 * M[6] + p2 * M[10];
                N[r*4+3] = p0 * M[3] + p1 * M[7] + p2 * M[11] + p3;
            }
            #pragma unroll
            for (int j = 0; j < 12; j++) M[j] = N[j];
        }

        const float* jp = J + ((size_t)b * NJ + i) * 3;
        float jx = jp[0], jy = jp[1], jz = jp[2];
        #pragma unroll
        for (int r = 0; r < 3; r++) {
            float g0 = M[r*4+0], g1 = M[r*4+1], g2 = M[r*4+2], g3 = M[r*4+3];
            float corr = g0 * jx + g1 * jy + g2 * jz;
            Gc_lds[i*12 + r*4+0] = g0;
            Gc_lds[i*12 + r*4+1] = g1;
            Gc_lds[i*12 + r*4+2] = g2;
            Gc_lds[i*12 + r*4+3] = g3 - corr;
        }
    }
    __syncthreads();

    // ---- Phase 1: MFMA skinning over 8 rounds ----
    float* mytl = &tl[wave * 32 * TLSTRIDE];

    // B fragment: B[k][n] = Gc[joint k][elem n], k = 8g + j; zero-padded.
    bf16x8 bfrag;
    #pragma unroll
    for (int j = 0; j < 8; j++) {
        const int k = 8 * g + j;
        const float gval = (k < NJ && n16 < 12) ? Gc_lds[k * 12 + n16] : 0.0f;
        bfrag[j] = f2bf(gval);
    }

    #pragma unroll
    for (int r = 0; r < NR; r++) {
        // Drain this round's staging (issued 2 rounds ago) + join all waves.
        asm volatile("s_waitcnt vmcnt(0)" ::: "memory");
        __syncthreads();

        // Prefetch: stage round r+2, V for round r+1 (latency hides under
        // this round's LDS/MFMA/epilogue across 12 waves/CU).
        if (r + 2 < NR)
            stage_round(wbase + (r + 2) * VPR * 24, Wbuf[(r + 2) % 3], tid);
        const float vcx = vnx, vcy = vny, vcz = vnz;
        if (lane < 32 && r + 1 < NR) {
            const float* vp = V + ((size_t)b * NV + vstart + (r + 1) * VPR
                                   + wave * 32 + lane) * 3;
            vnx = vp[0]; vny = vp[1]; vnz = vp[2];
        }

        // Compute: wave handles 32 verts = 2 MFMA tiles from Wbuf[r%3].
        const float* wb = Wbuf[r % 3];
        #pragma unroll
        for (int t = 0; t < 2; t++) {
            const int lv = wave * 32 + t * 16 + n16;   // local vert in round
            bf16x8 afrag;
            if (g < 3) {
                f32x4 lo = *(const f32x4*)&wb[lv * 24 + g * 8];
                f32x4 hi = *(const f32x4*)&wb[lv * 24 + g * 8 + 4];
                #pragma unroll
                for (int j = 0; j < 4; j++) { afrag[j] = f2bf(lo[j]); afrag[4+j] = f2bf(hi[j]); }
            } else {
                #pragma unroll
                for (int j = 0; j < 8; j++) afrag[j] = 0;
            }
            f32x4 acc = {0.f, 0.f, 0.f, 0.f};
            acc = __builtin_amdgcn_mfma_f32_16x16x32_bf16(afrag, bfrag, acc, 0, 0, 0);
            #pragma unroll
            for (int rr = 0; rr < 4; rr++)
                mytl[(t * 16 + 4 * g + rr) * TLSTRIDE + n16] = acc[rr];
        }

        __builtin_amdgcn_wave_barrier();

        // Epilogue: lanes 0..31 each finish one vert of this wave's 32.
        if (lane < 32) {
            const float* row = &mytl[lane * TLSTRIDE];
            f32x4 t0 = *(const f32x4*)(row + 0);
            f32x4 t1 = *(const f32x4*)(row + 4);
            f32x4 t2 = *(const f32x4*)(row + 8);
            float* op = out + ((size_t)b * NV + vstart + r * VPR
                               + wave * 32 + lane) * 3;
            op[0] = t0[0] * vcx + t0[1] * vcy + t0[2] * vcz + t0[3];
            op[1] = t1[0] * vcx + t1[1] * vcy + t1[2] * vcz + t1[3];
            op[2] = t2[0] * vcx + t2[1] * vcy + t2[2] * vcz + t2[3];
        }
        __builtin_amdgcn_wave_barrier();
    }
}

extern "C" void kernel_launch(void* const* d_in, const int* in_sizes, int n_in,
                              void* d_out, int out_size, void* d_ws, size_t ws_size,
                              hipStream_t stream) {
    const float* V    = (const float*)d_in[0];
    const float* J    = (const float*)d_in[1];
    const float* pose = (const float*)d_in[2];
    const float* W    = (const float*)d_in[3];
    float* out = (float*)d_out;

    dim3 grid((NV + VPB - 1) / VPB, NB);
    lbs_fused<<<grid, 256, 0, stream>>>(V, J, pose, W, out);
}

// Round 15
// 24.412 us; speedup vs baseline: 1.3251x; 1.3251x over previous
//
#include <hip/hip_runtime.h>
#include <math.h>
#include <string.h>

#define NJ 24
#define NV 6890
#define NB 128

// Ancestor chains (closest ancestor first), -1 padded. Max depth 8.
__constant__ int d_anc[NJ][8] = {
  {-1,-1,-1,-1,-1,-1,-1,-1},
  { 0,-1,-1,-1,-1,-1,-1,-1},
  { 0,-1,-1,-1,-1,-1,-1,-1},
  { 0,-1,-1,-1,-1,-1,-1,-1},
  { 1, 0,-1,-1,-1,-1,-1,-1},
  { 2, 0,-1,-1,-1,-1,-1,-1},
  { 3, 0,-1,-1,-1,-1,-1,-1},
  { 4, 1, 0,-1,-1,-1,-1,-1},
  { 5, 2, 0,-1,-1,-1,-1,-1},
  { 6, 3, 0,-1,-1,-1,-1,-1},
  { 7, 4, 1, 0,-1,-1,-1,-1},
  { 8, 5, 2, 0,-1,-1,-1,-1},
  { 9, 6, 3, 0,-1,-1,-1,-1},
  { 9, 6, 3, 0,-1,-1,-1,-1},
  { 9, 6, 3, 0,-1,-1,-1,-1},
  {12, 9, 6, 3, 0,-1,-1,-1},
  {13, 9, 6, 3, 0,-1,-1,-1},
  {14, 9, 6, 3, 0,-1,-1,-1},
  {16,13, 9, 6, 3, 0,-1,-1},
  {17,14, 9, 6, 3, 0,-1,-1},
  {18,16,13, 9, 6, 3, 0,-1},
  {19,17,14, 9, 6, 3, 0,-1},
  {20,18,16,13, 9, 6, 3, 0},
  {21,19,17,14, 9, 6, 3, 0}
};
__constant__ int d_par[NJ] = {-1,0,0,0,1,2,3,4,5,6,7,8,9,9,9,12,13,14,16,17,18,19,20,21};

typedef __attribute__((ext_vector_type(8))) short bf16x8;
typedef __attribute__((ext_vector_type(4))) float f32x4;

__device__ __forceinline__ short f2bf(float f) {
    unsigned int u;
    memcpy(&u, &f, 4);
    u += 0x7fffu + ((u >> 16) & 1u);   // round-to-nearest-even
    return (short)(u >> 16);
}

#define TLSTRIDE 20   // floats per scratch row: 80 B, 16B-aligned

// FUSED kernel (empirical best, R11 form): per-block redundant chain (7
// blocks/batch recompute the 24 joint transforms on one wave -- hidden under
// the other waves' memory streams), then MFMA skinning:
// T[b] (6890x12) = W[b] (6890x24) @ Gc[b] (24x12) per 16-vert MFMA tile
// (K zero-padded 24->32, N 12->16); B-fragment read once per wave from LDS.
// Per 14 rounds of probing: the skinning phase sits on a ~5 TB/s mixed
// L3/HBM supply plateau; instruction-count, wave-count, coalescing, and
// prefetch-depth levers are all null -- this loose compiler-scheduled form
// is the operating point that wins.
__global__ __launch_bounds__(256) void lbs_fused(const float* __restrict__ V,
                                                 const float* __restrict__ J,
                                                 const float* __restrict__ pose,
                                                 const float* __restrict__ W,
                                                 float* __restrict__ out) {
    const int b   = blockIdx.y;
    const int tid = threadIdx.x;

    __shared__ float A_lds[NJ][12];     // local [R|t] per joint
    __shared__ float Gc_lds[NJ * 12];   // corrected global transforms
    __shared__ float tl[4 * 64 * TLSTRIDE];   // epilogue transpose scratch

    // ---- Phase 0: chain (all threads reach both barriers) ----
    if (tid < NJ) {
        const int i = tid;
        const float* p = pose + ((size_t)b * NJ + i) * 3;
        float rx = p[0], ry = p[1], rz = p[2];
        float ex = rx + 1e-8f, ey = ry + 1e-8f, ez = rz + 1e-8f;
        float theta = sqrtf(ex * ex + ey * ey + ez * ez);
        float inv = 1.0f / theta;
        float hx = rx * inv, hy = ry * inv, hz = rz * inv;
        float c = cosf(theta * (float)M_PI);
        float s = sinf(theta);
        float oc = 1.0f - c;
        const float* jp = J + ((size_t)b * NJ + i) * 3;
        int par = d_par[i];
        float tx, ty, tz;
        if (par < 0) {
            tx = jp[0]; ty = jp[1]; tz = jp[2];
        } else {
            const float* jq = J + ((size_t)b * NJ + par) * 3;
            tx = jp[0] - jq[0]; ty = jp[1] - jq[1]; tz = jp[2] - jq[2];
        }
        A_lds[i][0]  = c + oc * hx * hx;
        A_lds[i][1]  = oc * hx * hy - s * hz;
        A_lds[i][2]  = oc * hx * hz + s * hy;
        A_lds[i][3]  = tx;
        A_lds[i][4]  = oc * hy * hx + s * hz;
        A_lds[i][5]  = c + oc * hy * hy;
        A_lds[i][6]  = oc * hy * hz - s * hx;
        A_lds[i][7]  = ty;
        A_lds[i][8]  = oc * hz * hx - s * hy;
        A_lds[i][9]  = oc * hz * hy + s * hx;
        A_lds[i][10] = c + oc * hz * hz;
        A_lds[i][11] = tz;
    }
    __syncthreads();

    if (tid < NJ) {
        const int i = tid;
        float M[12];
        #pragma unroll
        for (int j = 0; j < 12; j++) M[j] = A_lds[i][j];

        for (int k = 0; k < 8; k++) {
            int p = d_anc[i][k];
            if (p < 0) break;
            float P[12];
            #pragma unroll
            for (int j = 0; j < 12; j++) P[j] = A_lds[p][j];
            float N[12];
            #pragma unroll
            for (int r = 0; r < 3; r++) {
                float p0 = P[r*4+0], p1 = P[r*4+1], p2 = P[r*4+2], p3 = P[r*4+3];
                N[r*4+0] = p0 * M[0] + p1 * M[4] + p2 * M[8];
                N[r*4+1] = p0 * M[1] + p1 * M[5] + p2 * M[9];
                N[r*4+2] = p0 * M[2] + p1 * M[6] + p2 * M[10];
                N[r*4+3] = p0 * M[3] + p1 * M[7] + p2 * M[11] + p3;
            }
            #pragma unroll
            for (int j = 0; j < 12; j++) M[j] = N[j];
        }

        const float* jp = J + ((size_t)b * NJ + i) * 3;
        float jx = jp[0], jy = jp[1], jz = jp[2];
        #pragma unroll
        for (int r = 0; r < 3; r++) {
            float g0 = M[r*4+0], g1 = M[r*4+1], g2 = M[r*4+2], g3 = M[r*4+3];
            float corr = g0 * jx + g1 * jy + g2 * jz;
            Gc_lds[i*12 + r*4+0] = g0;
            Gc_lds[i*12 + r*4+1] = g1;
            Gc_lds[i*12 + r*4+2] = g2;
            Gc_lds[i*12 + r*4+3] = g3 - corr;
        }
    }
    __syncthreads();

    // ---- Phase 1: MFMA skinning ----
    const int wave  = tid >> 6;
    const int lane  = tid & 63;
    const int vwave = blockIdx.x * 1024 + wave * 256;   // 256 verts per wave
    if (vwave >= NV) return;

    float* mytl = &tl[wave * 64 * TLSTRIDE];

    const int n16 = lane & 15;   // A: vertex slot | B: out-element n | C: col
    const int g   = lane >> 4;   // k-group (8 joints per group)

    // B fragment: B[k][n] = Gc[joint k][elem n], k = 8g + j; zero-pad
    // k>=24 and n>=12. Read once per wave (8 ds_read per lane).
    bf16x8 bfrag;
    #pragma unroll
    for (int j = 0; j < 8; j++) {
        const int k = 8 * g + j;
        const float gval = (k < NJ && n16 < 12) ? Gc_lds[k * 12 + n16] : 0.0f;
        bfrag[j] = f2bf(gval);
    }

    #pragma unroll 1
    for (int grp = 0; grp < 4; grp++) {
        const int gbase = vwave + grp * 64;

        #pragma unroll
        for (int t = 0; t < 4; t++) {
            const int tb = gbase + t * 16;
            const int v  = tb + n16;
            const int vc = v < NV ? v : NV - 1;

            // A fragment: W[vert v][k=8g..8g+7] as two aligned float4 (g<3).
            f32x4 lo = {0.f, 0.f, 0.f, 0.f}, hi = {0.f, 0.f, 0.f, 0.f};
            if (g < 3) {
                const float4* wp =
                    (const float4*)(W + ((size_t)b * NV + vc) * 24 + g * 8);
                float4 l4 = wp[0];
                float4 h4 = wp[1];
                lo[0] = l4.x; lo[1] = l4.y; lo[2] = l4.z; lo[3] = l4.w;
                hi[0] = h4.x; hi[1] = h4.y; hi[2] = h4.z; hi[3] = h4.w;
            }
            bf16x8 afrag;
            #pragma unroll
            for (int j = 0; j < 4; j++) afrag[j]     = f2bf(lo[j]);
            #pragma unroll
            for (int j = 0; j < 4; j++) afrag[4 + j] = f2bf(hi[j]);

            f32x4 acc = {0.f, 0.f, 0.f, 0.f};
            acc = __builtin_amdgcn_mfma_f32_16x16x32_bf16(afrag, bfrag, acc, 0, 0, 0);

            // C: lane holds rows 4g+r (vertex within tile), col n16 (T elem).
            #pragma unroll
            for (int r = 0; r < 4; r++) {
                const int lv = t * 16 + 4 * g + r;   // local vert within group
                mytl[lv * TLSTRIDE + n16] = acc[r];
            }
        }

        // Wave-synchronous LDS RAW within one wave; no cross-wave sharing.
        __builtin_amdgcn_wave_barrier();

        // Epilogue: one vert per lane (64 verts of this group).
        const int gv  = gbase + lane;
        const int gvc = gv < NV ? gv : NV - 1;
        const float* row = &mytl[lane * TLSTRIDE];
        f32x4 t0 = *(const f32x4*)(row + 0);   // T[0..3]
        f32x4 t1 = *(const f32x4*)(row + 4);   // T[4..7]
        f32x4 t2 = *(const f32x4*)(row + 8);   // T[8..11]

        const float* vp = V + ((size_t)b * NV + gvc) * 3;
        const float vx = vp[0], vy = vp[1], vz = vp[2];
        if (gv < NV) {
            float* op = out + ((size_t)b * NV + gv) * 3;
            op[0] = t0[0] * vx + t0[1] * vy + t0[2] * vz + t0[3];
            op[1] = t1[0] * vx + t1[1] * vy + t1[2] * vz + t1[3];
            op[2] = t2[0] * vx + t2[1] * vy + t2[2] * vz + t2[3];
        }
        __builtin_amdgcn_wave_barrier();   // keep next group's writes after reads
    }
}

extern "C" void kernel_launch(void* const* d_in, const int* in_sizes, int n_in,
                              void* d_out, int out_size, void* d_ws, size_t ws_size,
                              hipStream_t stream) {
    const float* V    = (const float*)d_in[0];
    const float* J    = (const float*)d_in[1];
    const float* pose = (const float*)d_in[2];
    const float* W    = (const float*)d_in[3];
    float* out = (float*)d_out;

    dim3 grid((NV + 1023) / 1024, NB);
    lbs_fused<<<grid, 256, 0, stream>>>(V, J, pose, W, out);
}